// Round 17
// baseline (357.284 us; speedup 1.0000x reference)
//
#include <hip/hip_runtime.h>
#include <hip/hip_bf16.h>

#define NN 50000
#define NE 800000
#define NB 512
#define WT_S 136           // padded k-stride (bf16 elems) for transposed W
#define WT_M (128 * WT_S)  // elems per transposed weight matrix
#define DCAP 64            // padded CSR row capacity (deg ~ Poisson(16))
#define PCSRB ((NE + 255) / 256)  // 3125 pcsr blocks
#define PREPB 704                 // prep blocks
#define GNB 782            // gather node-blocks per feature-phase (64 nodes each)

using u32 = unsigned int;
using u16 = unsigned short;
typedef __attribute__((ext_vector_type(8))) short short8;
typedef __attribute__((ext_vector_type(4))) float f32x4;

constexpr float BNS = 0.9999950000374998f;  // 1/sqrt(1+1e-5)

__device__ inline u16 f2bf(float f) {
    u32 b = __builtin_bit_cast(u32, f);
    return (u16)((b + 0x7FFFu + ((b >> 16) & 1u)) >> 16);
}
__device__ inline float bf2f(u32 u) {
    return __builtin_bit_cast(float, u << 16);
}
__device__ inline u32 pk2(float a, float b) {
    return (u32)f2bf(a) | ((u32)f2bf(b) << 16);
}

// ---------------- build: pcsr (blocks < PCSRB) + wprep/setup (rest) ----------------
__global__ void k_build(const int* __restrict__ ei, const int* __restrict__ batch,
                        int* __restrict__ deg, u32* __restrict__ nbr,
                        const float* __restrict__ nW, const float* __restrict__ cW1,
                        const float* __restrict__ cW2, u16* __restrict__ wt,
                        const float* __restrict__ vn_emb, float* __restrict__ vn,
                        u16* __restrict__ vnb, int* __restrict__ bstart,
                        float* __restrict__ counts) {
    if (blockIdx.x < PCSRB) {
        int e = blockIdx.x * 256 + threadIdx.x;
        if (e >= NE) return;
        int src = ei[e];
        int dst = ei[NE + e];
        int pos = atomicAdd(&deg[dst], 1);
        if (pos < DCAP) nbr[(size_t)dst * DCAP + pos] = (u32)src | ((u32)batch[src] << 16);
        return;
    }
    int bb = blockIdx.x - PCSRB;
    if (bb < 448) {
        int idx = bb * 256 + threadIdx.x;  // < 7*16384
        int m = idx >> 14, e = idx & 16383;
        int k = e >> 7, c = e & 127;
        const float* src = m == 0 ? nW : (m <= 3 ? cW1 + (m - 1) * 16384 : cW2 + (m - 4) * 16384);
        wt[m * WT_M + c * WT_S + k] = f2bf(src[e]);
        return;
    }
    int idx = (bb - 448) * 256 + threadIdx.x;
    if (idx < NB * 128) {
        float v = vn_emb[idx & 127];
        vn[idx] = v;
        vnb[idx] = f2bf(v);
    }
    if (idx <= NB) {
        int b = idx;
        int lo = 0, hi = NN;
        while (lo < hi) { int m = (lo + hi) >> 1; if (batch[m] < b) lo = m + 1; else hi = m; }
        bstart[b] = lo;
        if (b < NB) {
            int b1 = b + 1, lo1 = 0, hi1 = NN;
            while (lo1 < hi1) { int m = (lo1 + hi1) >> 1; if (batch[m] < b1) lo1 = m + 1; else hi1 = m; }
            counts[b] = (float)(lo1 - lo);
        }
    }
}

__device__ __forceinline__ void acc8(float* A, uint4 U) {
    A[0] += bf2f(U.x & 0xFFFFu); A[1] += bf2f(U.x >> 16);
    A[2] += bf2f(U.y & 0xFFFFu); A[3] += bf2f(U.y >> 16);
    A[4] += bf2f(U.z & 0xFFFFu); A[5] += bf2f(U.z >> 16);
    A[6] += bf2f(U.w & 0xFFFFu); A[7] += bf2f(U.w >> 16);
}

// ---------------- gather: column-phased (4 phases x 32 features), node-major layout ----------------
// phase fg = blockIdx/GNB; 64 nodes/block, 4 lanes/node, lane q = (t&3)+fg*4 (uint4 col)
// per-phase hb0 working set = 50000 x 64B = 3.2MB -> fits per-XCD L2
__global__ __launch_bounds__(256) void k_gather(
    const int* __restrict__ deg, const u32* __restrict__ nbr,
    const u16* __restrict__ hb0, const u16* __restrict__ vnb,
    const int* __restrict__ batch, u16* __restrict__ ah, u16* __restrict__ alo) {
    const int fg = blockIdx.x / GNB;
    const int nb_ = blockIdx.x % GNB;
    const int node = nb_ * 64 + (threadIdx.x >> 2);
    const int q = (threadIdx.x & 3) + fg * 4;  // uint4 index within 256B row
    if (node >= NN) return;
    const uint4* h4 = (const uint4*)hb0;
    const uint4* v4 = (const uint4*)vnb;
    const u32* nbp = nbr + (size_t)node * DCAP;
    const int n = min(deg[node], DCAP);

    float a[8], b[8];
    {
        uint4 vd = h4[(size_t)node * 16 + q];
        uint4 wd = v4[(size_t)batch[node] * 16 + q];
        a[0] = bf2f(vd.x & 0xFFFFu) + bf2f(wd.x & 0xFFFFu);
        a[1] = bf2f(vd.x >> 16) + bf2f(wd.x >> 16);
        a[2] = bf2f(vd.y & 0xFFFFu) + bf2f(wd.y & 0xFFFFu);
        a[3] = bf2f(vd.y >> 16) + bf2f(wd.y >> 16);
        a[4] = bf2f(vd.z & 0xFFFFu) + bf2f(wd.z & 0xFFFFu);
        a[5] = bf2f(vd.z >> 16) + bf2f(wd.z >> 16);
        a[6] = bf2f(vd.w & 0xFFFFu) + bf2f(wd.w & 0xFFFFu);
        a[7] = bf2f(vd.w >> 16) + bf2f(wd.w >> 16);
    }
#pragma unroll
    for (int i = 0; i < 8; ++i) b[i] = 0.f;

    int j = 0;
    for (; j + 3 < n; j += 4) {
        uint4 nn = *(const uint4*)(nbp + j);
        uint4 h0 = h4[(size_t)(nn.x & 0xFFFFu) * 16 + q];
        uint4 v0 = v4[(size_t)(nn.x >> 16) * 16 + q];
        uint4 h1 = h4[(size_t)(nn.y & 0xFFFFu) * 16 + q];
        uint4 v1 = v4[(size_t)(nn.y >> 16) * 16 + q];
        uint4 h2 = h4[(size_t)(nn.z & 0xFFFFu) * 16 + q];
        uint4 v2 = v4[(size_t)(nn.z >> 16) * 16 + q];
        uint4 h3 = h4[(size_t)(nn.w & 0xFFFFu) * 16 + q];
        uint4 v3 = v4[(size_t)(nn.w >> 16) * 16 + q];
        acc8(a, h0); acc8(a, v0);
        acc8(b, h1); acc8(b, v1);
        acc8(a, h2); acc8(a, v2);
        acc8(b, h3); acc8(b, v3);
    }
    for (; j < n; ++j) {
        u32 e0 = nbp[j];
        uint4 h0 = h4[(size_t)(e0 & 0xFFFFu) * 16 + q];
        uint4 v0 = v4[(size_t)(e0 >> 16) * 16 + q];
        acc8(a, h0); acc8(a, v0);
    }
#pragma unroll
    for (int i = 0; i < 8; ++i) a[i] += b[i];

    u16 hi[8];
#pragma unroll
    for (int i = 0; i < 8; ++i) hi[i] = f2bf(a[i]);
    uint4 ho = {(u32)hi[0] | ((u32)hi[1] << 16), (u32)hi[2] | ((u32)hi[3] << 16),
                (u32)hi[4] | ((u32)hi[5] << 16), (u32)hi[6] | ((u32)hi[7] << 16)};
    uint4 lo = {pk2(a[0] - bf2f(hi[0]), a[1] - bf2f(hi[1])),
                pk2(a[2] - bf2f(hi[2]), a[3] - bf2f(hi[3])),
                pk2(a[4] - bf2f(hi[4]), a[5] - bf2f(hi[5])),
                pk2(a[6] - bf2f(hi[6]), a[7] - bf2f(hi[7]))};
    ((uint4*)ah)[(size_t)node * 16 + q] = ho;
    ((uint4*)alo)[(size_t)node * 16 + q] = lo;
}

// ---------------- node encoder GEMM: hb0 = bf16(x @ W + b), f32 A split in-kernel ----------------
__global__ __launch_bounds__(512) void k_gemm0(
    const float* __restrict__ Ap, const u16* __restrict__ wt,
    const float* __restrict__ bias, u16* __restrict__ outp) {
    __shared__ u16 sW[WT_M];
    const int t = threadIdx.x;
    {
        const float4* src = (const float4*)wt;
        float4* dst = (float4*)sW;
        for (int i = t; i < WT_M / 8; i += 512) dst[i] = src[i];
    }
    __syncthreads();
    const int lane = t & 63;
    const int w = t >> 6;  // 0..7
    const int rl = lane & 15;
    const int q = lane >> 4;
    const int rbase = blockIdx.x * 256 + w * 32;

    short8 af[2][4], al[2][4];
#pragma unroll
    for (int ri = 0; ri < 2; ++ri) {
        int row = min(rbase + ri * 16 + rl, NN - 1);
#pragma unroll
        for (int kc = 0; kc < 4; ++kc) {
            const float* ap = Ap + (size_t)row * 128 + kc * 32 + q * 8;
            float4 f0 = *(const float4*)ap;
            float4 f1 = *(const float4*)(ap + 4);
            float fv[8] = {f0.x, f0.y, f0.z, f0.w, f1.x, f1.y, f1.z, f1.w};
            short8 hi, lo;
#pragma unroll
            for (int i = 0; i < 8; ++i) {
                u16 hv = f2bf(fv[i]);
                hi[i] = (short)hv;
                lo[i] = (short)f2bf(fv[i] - bf2f(hv));
            }
            af[ri][kc] = hi;
            al[ri][kc] = lo;
        }
    }

#pragma unroll
    for (int ct = 0; ct < 8; ++ct) {
        f32x4 acc0 = {0.f, 0.f, 0.f, 0.f};
        f32x4 acc1 = {0.f, 0.f, 0.f, 0.f};
#pragma unroll
        for (int kc = 0; kc < 4; ++kc) {
            short8 bf = *(const short8*)&sW[(ct * 16 + rl) * WT_S + kc * 32 + q * 8];
            acc0 = __builtin_amdgcn_mfma_f32_16x16x32_bf16(al[0][kc], bf, acc0, 0, 0, 0);
            acc1 = __builtin_amdgcn_mfma_f32_16x16x32_bf16(al[1][kc], bf, acc1, 0, 0, 0);
            acc0 = __builtin_amdgcn_mfma_f32_16x16x32_bf16(af[0][kc], bf, acc0, 0, 0, 0);
            acc1 = __builtin_amdgcn_mfma_f32_16x16x32_bf16(af[1][kc], bf, acc1, 0, 0, 0);
        }
        const int col = ct * 16 + rl;
        const float bs = bias[col];
#pragma unroll
        for (int half = 0; half < 2; ++half) {
            const f32x4& ac = half ? acc1 : acc0;
#pragma unroll
            for (int i = 0; i < 4; ++i) {
                int r = rbase + half * 16 + q * 4 + i;
                if (r < NN) outp[(size_t)r * 128 + col] = f2bf(ac[i] + bs);
            }
        }
    }
}

// ---------------- fused conv: hb0 = leaky(bn(leaky(agg@W1+b1))@W2+b2) ----------------
// 128 rows/block, 256 threads. z tile staged in the same LDS buffer as W1 (reused).
__global__ __launch_bounds__(256) void k_conv(
    const u16* __restrict__ aggh, const u16* __restrict__ agglo,
    const u16* __restrict__ wt1, const float* __restrict__ bias1,
    const float* __restrict__ gg, const float* __restrict__ bb,
    const u16* __restrict__ wt2, const float* __restrict__ bias2,
    u16* __restrict__ hb0) {
    __shared__ u16 sZ[WT_M];  // 34816 B: W1 stage, then z tile [128][WT_S]
    const int t = threadIdx.x;
    const int lane = t & 63;
    const int w = t >> 6;  // 0..3
    const int rl = lane & 15;
    const int q = lane >> 4;
    const int lbase = w * 32;
    const int rbase = blockIdx.x * 128 + lbase;

    // A fragments (agg hi/lo) issued before W1 staging to overlap latency
    short8 af[2][4], al[2][4];
#pragma unroll
    for (int ri = 0; ri < 2; ++ri) {
        int row = min(rbase + ri * 16 + rl, NN - 1);
#pragma unroll
        for (int kc = 0; kc < 4; ++kc) {
            af[ri][kc] = *(const short8*)(aggh + (size_t)row * 128 + kc * 32 + q * 8);
            al[ri][kc] = *(const short8*)(agglo + (size_t)row * 128 + kc * 32 + q * 8);
        }
    }
    {
        const float4* src = (const float4*)wt1;
        float4* dst = (float4*)sZ;
        for (int i = t; i < WT_M / 8; i += 256) dst[i] = src[i];
    }
    __syncthreads();

    // GEMM1 + epi2 -> z in registers
    float zs[8][8];
#pragma unroll
    for (int ct = 0; ct < 8; ++ct) {
        f32x4 acc0 = {0.f, 0.f, 0.f, 0.f};
        f32x4 acc1 = {0.f, 0.f, 0.f, 0.f};
#pragma unroll
        for (int kc = 0; kc < 4; ++kc) {
            short8 bf = *(const short8*)&sZ[(ct * 16 + rl) * WT_S + kc * 32 + q * 8];
            acc0 = __builtin_amdgcn_mfma_f32_16x16x32_bf16(al[0][kc], bf, acc0, 0, 0, 0);
            acc1 = __builtin_amdgcn_mfma_f32_16x16x32_bf16(al[1][kc], bf, acc1, 0, 0, 0);
            acc0 = __builtin_amdgcn_mfma_f32_16x16x32_bf16(af[0][kc], bf, acc0, 0, 0, 0);
            acc1 = __builtin_amdgcn_mfma_f32_16x16x32_bf16(af[1][kc], bf, acc1, 0, 0, 0);
        }
        const int col = ct * 16 + rl;
        const float bs = bias1[col];
        const float g = gg[col];
        const float be = bb[col];
#pragma unroll
        for (int i = 0; i < 4; ++i) {
            float v0 = acc0[i] + bs;
            v0 = v0 > 0.f ? v0 : 0.2f * v0;
            zs[ct][i] = g * v0 * BNS + be;
            float v1 = acc1[i] + bs;
            v1 = v1 > 0.f ? v1 : 0.2f * v1;
            zs[ct][4 + i] = g * v1 * BNS + be;
        }
    }
    __syncthreads();

    // stage z tile (bf16) into sZ, overwriting W1
#pragma unroll
    for (int ct = 0; ct < 8; ++ct) {
        const int col = ct * 16 + rl;
#pragma unroll
        for (int i = 0; i < 4; ++i) {
            sZ[(lbase + q * 4 + i) * WT_S + col] = f2bf(zs[ct][i]);
            sZ[(lbase + 16 + q * 4 + i) * WT_S + col] = f2bf(zs[ct][4 + i]);
        }
    }
    __syncthreads();

    // GEMM2: A = z from LDS, B = W2 from global (L2-hot)
    short8 zf[2][4];
#pragma unroll
    for (int ri = 0; ri < 2; ++ri)
#pragma unroll
        for (int kc = 0; kc < 4; ++kc)
            zf[ri][kc] = *(const short8*)&sZ[(lbase + ri * 16 + rl) * WT_S + kc * 32 + q * 8];

#pragma unroll
    for (int ct = 0; ct < 8; ++ct) {
        f32x4 acc0 = {0.f, 0.f, 0.f, 0.f};
        f32x4 acc1 = {0.f, 0.f, 0.f, 0.f};
#pragma unroll
        for (int kc = 0; kc < 4; ++kc) {
            short8 bf = *(const short8*)(wt2 + (size_t)(ct * 16 + rl) * WT_S + kc * 32 + q * 8);
            acc0 = __builtin_amdgcn_mfma_f32_16x16x32_bf16(zf[0][kc], bf, acc0, 0, 0, 0);
            acc1 = __builtin_amdgcn_mfma_f32_16x16x32_bf16(zf[1][kc], bf, acc1, 0, 0, 0);
        }
        const int col = ct * 16 + rl;
        const float bs = bias2[col];
#pragma unroll
        for (int half = 0; half < 2; ++half) {
            const f32x4& ac = half ? acc1 : acc0;
#pragma unroll
            for (int i = 0; i < 4; ++i) {
                int r = rbase + half * 16 + q * 4 + i;
                if (r < NN) {
                    float v = ac[i] + bs;
                    v = v > 0.f ? v : 0.2f * v;
                    hb0[(size_t)r * 128 + col] = f2bf(v);
                }
            }
        }
    }
}

// ---------------- fused pool(bf16 hb0) + vn MLP; writes vn + bf16 mirror ----------------
__global__ __launch_bounds__(256) void k_vnup(
    const u16* __restrict__ hb0, const int* __restrict__ bstart,
    const float* __restrict__ counts, const float* __restrict__ W1,
    const float* __restrict__ b1, const float* __restrict__ W2,
    const float* __restrict__ b2, float* __restrict__ vn, u16* __restrict__ vnb) {
    __shared__ float4 red[8][32];
    __shared__ float sP[128], sT[128], sH[2][128];
    const int b = blockIdx.x;
    const int t = threadIdx.x;
    const int s = bstart[b], e = bstart[b + 1];
    const int g = t >> 5, q = t & 31;
    const uint2* h2 = (const uint2*)hb0;
    float4 a = make_float4(0.f, 0.f, 0.f, 0.f);
    for (int r = s + g; r < e; r += 8) {
        uint2 v = h2[(size_t)r * 32 + q];
        a.x += bf2f(v.x & 0xFFFFu); a.y += bf2f(v.x >> 16);
        a.z += bf2f(v.y & 0xFFFFu); a.w += bf2f(v.y >> 16);
    }
    red[g][q] = a;
    __syncthreads();
    if (g == 0) {
#pragma unroll
        for (int g2 = 1; g2 < 8; ++g2) {
            float4 v = red[g2][q];
            a.x += v.x; a.y += v.y; a.z += v.z; a.w += v.w;
        }
        float inv = 1.f / fmaxf(counts[b], 1.f);
        sP[q * 4 + 0] = a.x * inv;
        sP[q * 4 + 1] = a.y * inv;
        sP[q * 4 + 2] = a.z * inv;
        sP[q * 4 + 3] = a.w * inv;
    }
    __syncthreads();
    {
        const int c = t & 127, hf = t >> 7;
        float acc = 0.f;
        const float* Wp = W1 + (size_t)(hf * 64) * 128 + c;
#pragma unroll 8
        for (int k = 0; k < 64; ++k) acc += sP[hf * 64 + k] * Wp[(size_t)k * 128];
        sH[hf][c] = acc;
    }
    __syncthreads();
    if (t < 128) {
        float v = sH[0][t] + sH[1][t] + b1[t];
        sT[t] = v > 0.f ? v : 0.2f * v;
    }
    __syncthreads();
    {
        const int c = t & 127, hf = t >> 7;
        float acc = 0.f;
        const float* Wp = W2 + (size_t)(hf * 64) * 128 + c;
#pragma unroll 8
        for (int k = 0; k < 64; ++k) acc += sT[hf * 64 + k] * Wp[(size_t)k * 128];
        sH[hf][c] = acc;
    }
    __syncthreads();
    if (t < 128) {
        float nv = vn[(size_t)b * 128 + t] + sH[0][t] + sH[1][t] + b2[t];
        vn[(size_t)b * 128 + t] = nv;
        vnb[(size_t)b * 128 + t] = f2bf(nv);
    }
}

// ---------------- final: pool(bf16 hb0) + BN + fc  (4 batches per block) ----------------
__global__ __launch_bounds__(256) void k_final(
    const u16* __restrict__ hb0, const int* __restrict__ bstart,
    const float* __restrict__ g, const float* __restrict__ bB,
    const float* __restrict__ fcW, const float* __restrict__ fcb,
    float* __restrict__ out) {
    __shared__ float sP[4][128];
    __shared__ float4 red[4][2][32];
    const int t = threadIdx.x;
    const int seg = t >> 6, gq = t & 63, rg = gq >> 5, q = gq & 31;
    const int b = blockIdx.x * 4 + seg;
    const int s = bstart[b], e = bstart[b + 1];
    const uint2* h2 = (const uint2*)hb0;
    float4 a = make_float4(0.f, 0.f, 0.f, 0.f);
    for (int r = s + rg; r < e; r += 2) {
        uint2 v = h2[(size_t)r * 32 + q];
        a.x += bf2f(v.x & 0xFFFFu); a.y += bf2f(v.x >> 16);
        a.z += bf2f(v.y & 0xFFFFu); a.w += bf2f(v.y >> 16);
    }
    red[seg][rg][q] = a;
    __syncthreads();
    if (rg == 0) {
        float4 v = red[seg][1][q];
        a.x += v.x; a.y += v.y; a.z += v.z; a.w += v.w;
        float av[4] = {a.x, a.y, a.z, a.w};
#pragma unroll
        for (int i = 0; i < 4; ++i) {
            int c = q * 4 + i;
            sP[seg][c] = g[c] * av[i] * BNS + bB[c];
        }
    }
    __syncthreads();
    const int o = t & 63;
    float acc = fcb[o];
    const float* wrow = fcW + o * 128;
    const float* prow = sP[seg];
    for (int k = 0; k < 128; ++k) acc += prow[k] * wrow[k];
    out[(size_t)b * 64 + o] = acc;
}

extern "C" void kernel_launch(void* const* d_in, const int* in_sizes, int n_in,
                              void* d_out, int out_size, void* d_ws, size_t ws_size,
                              hipStream_t stream) {
    const float* x       = (const float*)d_in[0];
    const int*   ei      = (const int*)d_in[1];
    const int*   batch   = (const int*)d_in[2];
    const float* node_W  = (const float*)d_in[3];
    const float* node_b  = (const float*)d_in[4];
    const float* conv_W1 = (const float*)d_in[5];
    const float* conv_b1 = (const float*)d_in[6];
    const float* conv_g  = (const float*)d_in[7];
    const float* conv_bt = (const float*)d_in[8];
    const float* conv_W2 = (const float*)d_in[9];
    const float* conv_b2 = (const float*)d_in[10];
    const float* vn_emb  = (const float*)d_in[11];
    const float* vn_W1   = (const float*)d_in[12];
    const float* vn_b1   = (const float*)d_in[13];
    const float* vn_W2   = (const float*)d_in[14];
    const float* vn_b2   = (const float*)d_in[15];
    const float* bn_g    = (const float*)d_in[16];
    const float* bn_b    = (const float*)d_in[17];
    const float* fc_W    = (const float*)d_in[18];
    const float* fc_b    = (const float*)d_in[19];
    float* out = (float*)d_out;

    char* ws = (char*)d_ws;
    u16* hb0   = (u16*)ws;                        // NN*128 bf16 (h, pre-vn)
    u16* aggh  = hb0 + (size_t)NN * 128;          // NN*128 bf16 (agg hi)
    u16* agglo = aggh + (size_t)NN * 128;         // NN*128 bf16 (agg lo)
    u16* wt    = agglo + (size_t)NN * 128;        // 7*WT_M bf16
    u32* nbr   = (u32*)(wt + 7 * WT_M);           // NN*DCAP u32 (padded CSR)
    float* vn  = (float*)(nbr + (size_t)NN * DCAP);  // NB*128 f32
    u16* vnb   = (u16*)(vn + NB * 128);           // NB*128 bf16
    float* counts = (float*)(vnb + NB * 128);     // NB
    int* bstart = (int*)(counts + NB);            // NB+1
    int* deg    = bstart + NB + 1;                // NN  <- zeroed

    hipMemsetAsync(deg, 0, NN * sizeof(int), stream);
    k_build<<<PCSRB + PREPB, 256, 0, stream>>>(ei, batch, deg, nbr, node_W, conv_W1,
                                               conv_W2, wt, vn_emb, vn, vnb, bstart, counts);

    // node encoder: hb0 = bf16(x @ node_W + node_b)
    k_gemm0<<<(NN + 255) / 256, 512, 0, stream>>>(x, wt, node_b, hb0);

    for (int l = 0; l < 3; ++l) {
        // agg (vn folded in) -> hi/lo split; 4 column-phases for L2 residency
        k_gather<<<4 * GNB, 256, 0, stream>>>(deg, nbr, hb0, vnb, batch, aggh, agglo);
        // hb0 = leaky(bn(leaky(agg@W1+b1))@W2+b2)  (fused, z stays in LDS)
        k_conv<<<(NN + 127) / 128, 256, 0, stream>>>(
            aggh, agglo, wt + (size_t)(1 + l) * WT_M, conv_b1 + l * 128,
            conv_g + l * 128, conv_bt + l * 128,
            wt + (size_t)(4 + l) * WT_M, conv_b2 + l * 128, hb0);
        // vn += mlp(pool(hb0)/denom)   (dead for l=2 -> skip)
        if (l < 2)
            k_vnup<<<NB, 256, 0, stream>>>(hb0, bstart, counts, vn_W1 + l * 16384,
                                           vn_b1 + l * 128, vn_W2 + l * 16384,
                                           vn_b2 + l * 128, vn, vnb);
    }

    k_final<<<NB / 4, 256, 0, stream>>>(hb0, bstart, bn_g, bn_b, fc_W, fc_b, out);
}

// Round 18
// 298.538 us; speedup vs baseline: 1.1968x; 1.1968x over previous
//
#include <hip/hip_runtime.h>
#include <hip/hip_bf16.h>

#define NN 50000
#define NE 800000
#define NB 512
#define WT_S 136           // padded k-stride (bf16 elems) for transposed W
#define WT_M (128 * WT_S)  // elems per transposed weight matrix
#define DCAP 64            // padded CSR row capacity (deg ~ Poisson(16))
#define GG0 ((NN + 255) / 256)     // 196 gemm0 blocks
#define PCSR512 ((NE + 511) / 512) // 1563 pcsr blocks @ 512 thr

using u32 = unsigned int;
using u16 = unsigned short;
typedef __attribute__((ext_vector_type(8))) short short8;
typedef __attribute__((ext_vector_type(4))) float f32x4;

constexpr float BNS = 0.9999950000374998f;  // 1/sqrt(1+1e-5)

__device__ inline u16 f2bf(float f) {
    u32 b = __builtin_bit_cast(u32, f);
    return (u16)((b + 0x7FFFu + ((b >> 16) & 1u)) >> 16);
}
__device__ inline float bf2f(u32 u) {
    return __builtin_bit_cast(float, u << 16);
}
__device__ inline u32 pk2(float a, float b) {
    return (u32)f2bf(a) | ((u32)f2bf(b) << 16);
}

// ---------------- prep: wprep (blocks 0..447) + setup (blocks 448..703) ----------------
__global__ void k_prep(const float* __restrict__ nW, const float* __restrict__ cW1,
                       const float* __restrict__ cW2, u16* __restrict__ wt,
                       const float* __restrict__ vn_emb, float* __restrict__ vn,
                       u16* __restrict__ vnb, const int* __restrict__ batch,
                       int* __restrict__ bstart, float* __restrict__ counts) {
    if (blockIdx.x < 448) {
        int idx = blockIdx.x * 256 + threadIdx.x;  // < 7*16384
        int m = idx >> 14, e = idx & 16383;
        int k = e >> 7, c = e & 127;
        const float* src = m == 0 ? nW : (m <= 3 ? cW1 + (m - 1) * 16384 : cW2 + (m - 4) * 16384);
        wt[m * WT_M + c * WT_S + k] = f2bf(src[e]);
        return;
    }
    int idx = (blockIdx.x - 448) * 256 + threadIdx.x;
    if (idx < NB * 128) {
        float v = vn_emb[idx & 127];
        vn[idx] = v;
        vnb[idx] = f2bf(v);
    }
    if (idx <= NB) {
        int b = idx;
        int lo = 0, hi = NN;
        while (lo < hi) { int m = (lo + hi) >> 1; if (batch[m] < b) lo = m + 1; else hi = m; }
        bstart[b] = lo;
        if (b < NB) {
            int b1 = b + 1, lo1 = 0, hi1 = NN;
            while (lo1 < hi1) { int m = (lo1 + hi1) >> 1; if (batch[m] < b1) lo1 = m + 1; else hi1 = m; }
            counts[b] = (float)(lo1 - lo);
        }
    }
}

// ---------------- enc: gemm0 (blocks 0..GG0-1) + pcsr scatter (blocks GG0..) ----------------
// independent workloads co-scheduled in one dispatch; pcsr hides gemm0
__global__ __launch_bounds__(512) void k_enc(
    const float* __restrict__ Ap, const u16* __restrict__ wt,
    const float* __restrict__ bias, u16* __restrict__ outp,
    const int* __restrict__ ei, const int* __restrict__ batch,
    int* __restrict__ deg, u32* __restrict__ nbr) {
    __shared__ u16 sW[WT_M];
    if (blockIdx.x >= GG0) {
        int e = (blockIdx.x - GG0) * 512 + threadIdx.x;
        if (e < NE) {
            int src = ei[e];
            int dst = ei[NE + e];
            int pos = atomicAdd(&deg[dst], 1);
            if (pos < DCAP) nbr[(size_t)dst * DCAP + pos] = (u32)src | ((u32)batch[src] << 16);
        }
        return;
    }
    const int t = threadIdx.x;
    {
        const float4* src = (const float4*)wt;
        float4* dst = (float4*)sW;
        for (int i = t; i < WT_M / 8; i += 512) dst[i] = src[i];
    }
    __syncthreads();
    const int lane = t & 63;
    const int w = t >> 6;  // 0..7
    const int rl = lane & 15;
    const int q = lane >> 4;
    const int rbase = blockIdx.x * 256 + w * 32;

    short8 af[2][4], al[2][4];
#pragma unroll
    for (int ri = 0; ri < 2; ++ri) {
        int row = min(rbase + ri * 16 + rl, NN - 1);
#pragma unroll
        for (int kc = 0; kc < 4; ++kc) {
            const float* ap = Ap + (size_t)row * 128 + kc * 32 + q * 8;
            float4 f0 = *(const float4*)ap;
            float4 f1 = *(const float4*)(ap + 4);
            float fv[8] = {f0.x, f0.y, f0.z, f0.w, f1.x, f1.y, f1.z, f1.w};
            short8 hi, lo;
#pragma unroll
            for (int i = 0; i < 8; ++i) {
                u16 hv = f2bf(fv[i]);
                hi[i] = (short)hv;
                lo[i] = (short)f2bf(fv[i] - bf2f(hv));
            }
            af[ri][kc] = hi;
            al[ri][kc] = lo;
        }
    }

#pragma unroll
    for (int ct = 0; ct < 8; ++ct) {
        f32x4 acc0 = {0.f, 0.f, 0.f, 0.f};
        f32x4 acc1 = {0.f, 0.f, 0.f, 0.f};
#pragma unroll
        for (int kc = 0; kc < 4; ++kc) {
            short8 bf = *(const short8*)&sW[(ct * 16 + rl) * WT_S + kc * 32 + q * 8];
            acc0 = __builtin_amdgcn_mfma_f32_16x16x32_bf16(al[0][kc], bf, acc0, 0, 0, 0);
            acc1 = __builtin_amdgcn_mfma_f32_16x16x32_bf16(al[1][kc], bf, acc1, 0, 0, 0);
            acc0 = __builtin_amdgcn_mfma_f32_16x16x32_bf16(af[0][kc], bf, acc0, 0, 0, 0);
            acc1 = __builtin_amdgcn_mfma_f32_16x16x32_bf16(af[1][kc], bf, acc1, 0, 0, 0);
        }
        const int col = ct * 16 + rl;
        const float bs = bias[col];
#pragma unroll
        for (int half = 0; half < 2; ++half) {
            const f32x4& ac = half ? acc1 : acc0;
#pragma unroll
            for (int i = 0; i < 4; ++i) {
                int r = rbase + half * 16 + q * 4 + i;
                if (r < NN) outp[(size_t)r * 128 + col] = f2bf(ac[i] + bs);
            }
        }
    }
}

__device__ __forceinline__ void acc8(float* A, uint4 U) {
    A[0] += bf2f(U.x & 0xFFFFu); A[1] += bf2f(U.x >> 16);
    A[2] += bf2f(U.y & 0xFFFFu); A[3] += bf2f(U.y >> 16);
    A[4] += bf2f(U.z & 0xFFFFu); A[5] += bf2f(U.z >> 16);
    A[6] += bf2f(U.w & 0xFFFFu); A[7] += bf2f(U.w >> 16);
}

// ---------------- gather: 16 lanes/node, uint4 loads, 4-edge unroll (R16 version) ----------------
__global__ __launch_bounds__(256) void k_gather(
    const int* __restrict__ deg, const u32* __restrict__ nbr,
    const u16* __restrict__ hb0, const u16* __restrict__ vnb,
    const int* __restrict__ batch, u16* __restrict__ ah, u16* __restrict__ alo) {
    const int node = blockIdx.x * 16 + (threadIdx.x >> 4);
    const int q = threadIdx.x & 15;  // uint4 index within 256B row
    if (node >= NN) return;
    const uint4* h4 = (const uint4*)hb0;
    const uint4* v4 = (const uint4*)vnb;
    const u32* nbp = nbr + (size_t)node * DCAP;
    const int n = min(deg[node], DCAP);

    float a[8], b[8];
    {
        uint4 vd = h4[(size_t)node * 16 + q];
        uint4 wd = v4[(size_t)batch[node] * 16 + q];
        a[0] = bf2f(vd.x & 0xFFFFu) + bf2f(wd.x & 0xFFFFu);
        a[1] = bf2f(vd.x >> 16) + bf2f(wd.x >> 16);
        a[2] = bf2f(vd.y & 0xFFFFu) + bf2f(wd.y & 0xFFFFu);
        a[3] = bf2f(vd.y >> 16) + bf2f(wd.y >> 16);
        a[4] = bf2f(vd.z & 0xFFFFu) + bf2f(wd.z & 0xFFFFu);
        a[5] = bf2f(vd.z >> 16) + bf2f(wd.z >> 16);
        a[6] = bf2f(vd.w & 0xFFFFu) + bf2f(wd.w & 0xFFFFu);
        a[7] = bf2f(vd.w >> 16) + bf2f(wd.w >> 16);
    }
#pragma unroll
    for (int i = 0; i < 8; ++i) b[i] = 0.f;

    int j = 0;
    for (; j + 3 < n; j += 4) {
        uint4 nn = *(const uint4*)(nbp + j);
        uint4 h0 = h4[(size_t)(nn.x & 0xFFFFu) * 16 + q];
        uint4 v0 = v4[(size_t)(nn.x >> 16) * 16 + q];
        uint4 h1 = h4[(size_t)(nn.y & 0xFFFFu) * 16 + q];
        uint4 v1 = v4[(size_t)(nn.y >> 16) * 16 + q];
        uint4 h2 = h4[(size_t)(nn.z & 0xFFFFu) * 16 + q];
        uint4 v2 = v4[(size_t)(nn.z >> 16) * 16 + q];
        uint4 h3 = h4[(size_t)(nn.w & 0xFFFFu) * 16 + q];
        uint4 v3 = v4[(size_t)(nn.w >> 16) * 16 + q];
        acc8(a, h0); acc8(a, v0);
        acc8(b, h1); acc8(b, v1);
        acc8(a, h2); acc8(a, v2);
        acc8(b, h3); acc8(b, v3);
    }
    for (; j < n; ++j) {
        u32 e0 = nbp[j];
        uint4 h0 = h4[(size_t)(e0 & 0xFFFFu) * 16 + q];
        uint4 v0 = v4[(size_t)(e0 >> 16) * 16 + q];
        acc8(a, h0); acc8(a, v0);
    }
#pragma unroll
    for (int i = 0; i < 8; ++i) a[i] += b[i];

    u16 hi[8];
#pragma unroll
    for (int i = 0; i < 8; ++i) hi[i] = f2bf(a[i]);
    uint4 ho = {(u32)hi[0] | ((u32)hi[1] << 16), (u32)hi[2] | ((u32)hi[3] << 16),
                (u32)hi[4] | ((u32)hi[5] << 16), (u32)hi[6] | ((u32)hi[7] << 16)};
    uint4 lo = {pk2(a[0] - bf2f(hi[0]), a[1] - bf2f(hi[1])),
                pk2(a[2] - bf2f(hi[2]), a[3] - bf2f(hi[3])),
                pk2(a[4] - bf2f(hi[4]), a[5] - bf2f(hi[5])),
                pk2(a[6] - bf2f(hi[6]), a[7] - bf2f(hi[7]))};
    ((uint4*)ah)[(size_t)node * 16 + q] = ho;
    ((uint4*)alo)[(size_t)node * 16 + q] = lo;
}

// ---------------- fused conv: hb0 = leaky(bn(leaky(agg@W1+b1))@W2+b2) ----------------
__global__ __launch_bounds__(256) void k_conv(
    const u16* __restrict__ aggh, const u16* __restrict__ agglo,
    const u16* __restrict__ wt1, const float* __restrict__ bias1,
    const float* __restrict__ gg, const float* __restrict__ bb,
    const u16* __restrict__ wt2, const float* __restrict__ bias2,
    u16* __restrict__ hb0) {
    __shared__ u16 sZ[WT_M];  // 34816 B: W1 stage, then z tile [128][WT_S]
    const int t = threadIdx.x;
    const int lane = t & 63;
    const int w = t >> 6;  // 0..3
    const int rl = lane & 15;
    const int q = lane >> 4;
    const int lbase = w * 32;
    const int rbase = blockIdx.x * 128 + lbase;

    short8 af[2][4], al[2][4];
#pragma unroll
    for (int ri = 0; ri < 2; ++ri) {
        int row = min(rbase + ri * 16 + rl, NN - 1);
#pragma unroll
        for (int kc = 0; kc < 4; ++kc) {
            af[ri][kc] = *(const short8*)(aggh + (size_t)row * 128 + kc * 32 + q * 8);
            al[ri][kc] = *(const short8*)(agglo + (size_t)row * 128 + kc * 32 + q * 8);
        }
    }
    {
        const float4* src = (const float4*)wt1;
        float4* dst = (float4*)sZ;
        for (int i = t; i < WT_M / 8; i += 256) dst[i] = src[i];
    }
    __syncthreads();

    float zs[8][8];
#pragma unroll
    for (int ct = 0; ct < 8; ++ct) {
        f32x4 acc0 = {0.f, 0.f, 0.f, 0.f};
        f32x4 acc1 = {0.f, 0.f, 0.f, 0.f};
#pragma unroll
        for (int kc = 0; kc < 4; ++kc) {
            short8 bf = *(const short8*)&sZ[(ct * 16 + rl) * WT_S + kc * 32 + q * 8];
            acc0 = __builtin_amdgcn_mfma_f32_16x16x32_bf16(al[0][kc], bf, acc0, 0, 0, 0);
            acc1 = __builtin_amdgcn_mfma_f32_16x16x32_bf16(al[1][kc], bf, acc1, 0, 0, 0);
            acc0 = __builtin_amdgcn_mfma_f32_16x16x32_bf16(af[0][kc], bf, acc0, 0, 0, 0);
            acc1 = __builtin_amdgcn_mfma_f32_16x16x32_bf16(af[1][kc], bf, acc1, 0, 0, 0);
        }
        const int col = ct * 16 + rl;
        const float bs = bias1[col];
        const float g = gg[col];
        const float be = bb[col];
#pragma unroll
        for (int i = 0; i < 4; ++i) {
            float v0 = acc0[i] + bs;
            v0 = v0 > 0.f ? v0 : 0.2f * v0;
            zs[ct][i] = g * v0 * BNS + be;
            float v1 = acc1[i] + bs;
            v1 = v1 > 0.f ? v1 : 0.2f * v1;
            zs[ct][4 + i] = g * v1 * BNS + be;
        }
    }
    __syncthreads();

#pragma unroll
    for (int ct = 0; ct < 8; ++ct) {
        const int col = ct * 16 + rl;
#pragma unroll
        for (int i = 0; i < 4; ++i) {
            sZ[(lbase + q * 4 + i) * WT_S + col] = f2bf(zs[ct][i]);
            sZ[(lbase + 16 + q * 4 + i) * WT_S + col] = f2bf(zs[ct][4 + i]);
        }
    }
    __syncthreads();

    short8 zf[2][4];
#pragma unroll
    for (int ri = 0; ri < 2; ++ri)
#pragma unroll
        for (int kc = 0; kc < 4; ++kc)
            zf[ri][kc] = *(const short8*)&sZ[(lbase + ri * 16 + rl) * WT_S + kc * 32 + q * 8];

#pragma unroll
    for (int ct = 0; ct < 8; ++ct) {
        f32x4 acc0 = {0.f, 0.f, 0.f, 0.f};
        f32x4 acc1 = {0.f, 0.f, 0.f, 0.f};
#pragma unroll
        for (int kc = 0; kc < 4; ++kc) {
            short8 bf = *(const short8*)(wt2 + (size_t)(ct * 16 + rl) * WT_S + kc * 32 + q * 8);
            acc0 = __builtin_amdgcn_mfma_f32_16x16x32_bf16(zf[0][kc], bf, acc0, 0, 0, 0);
            acc1 = __builtin_amdgcn_mfma_f32_16x16x32_bf16(zf[1][kc], bf, acc1, 0, 0, 0);
        }
        const int col = ct * 16 + rl;
        const float bs = bias2[col];
#pragma unroll
        for (int half = 0; half < 2; ++half) {
            const f32x4& ac = half ? acc1 : acc0;
#pragma unroll
            for (int i = 0; i < 4; ++i) {
                int r = rbase + half * 16 + q * 4 + i;
                if (r < NN) {
                    float v = ac[i] + bs;
                    v = v > 0.f ? v : 0.2f * v;
                    hb0[(size_t)r * 128 + col] = f2bf(v);
                }
            }
        }
    }
}

// ---------------- fused pool(bf16 hb0) + vn MLP; writes vn + bf16 mirror ----------------
__global__ __launch_bounds__(256) void k_vnup(
    const u16* __restrict__ hb0, const int* __restrict__ bstart,
    const float* __restrict__ counts, const float* __restrict__ W1,
    const float* __restrict__ b1, const float* __restrict__ W2,
    const float* __restrict__ b2, float* __restrict__ vn, u16* __restrict__ vnb) {
    __shared__ float4 red[8][32];
    __shared__ float sP[128], sT[128], sH[2][128];
    const int b = blockIdx.x;
    const int t = threadIdx.x;
    const int s = bstart[b], e = bstart[b + 1];
    const int g = t >> 5, q = t & 31;
    const uint2* h2 = (const uint2*)hb0;
    float4 a = make_float4(0.f, 0.f, 0.f, 0.f);
    for (int r = s + g; r < e; r += 8) {
        uint2 v = h2[(size_t)r * 32 + q];
        a.x += bf2f(v.x & 0xFFFFu); a.y += bf2f(v.x >> 16);
        a.z += bf2f(v.y & 0xFFFFu); a.w += bf2f(v.y >> 16);
    }
    red[g][q] = a;
    __syncthreads();
    if (g == 0) {
#pragma unroll
        for (int g2 = 1; g2 < 8; ++g2) {
            float4 v = red[g2][q];
            a.x += v.x; a.y += v.y; a.z += v.z; a.w += v.w;
        }
        float inv = 1.f / fmaxf(counts[b], 1.f);
        sP[q * 4 + 0] = a.x * inv;
        sP[q * 4 + 1] = a.y * inv;
        sP[q * 4 + 2] = a.z * inv;
        sP[q * 4 + 3] = a.w * inv;
    }
    __syncthreads();
    {
        const int c = t & 127, hf = t >> 7;
        float acc = 0.f;
        const float* Wp = W1 + (size_t)(hf * 64) * 128 + c;
#pragma unroll 8
        for (int k = 0; k < 64; ++k) acc += sP[hf * 64 + k] * Wp[(size_t)k * 128];
        sH[hf][c] = acc;
    }
    __syncthreads();
    if (t < 128) {
        float v = sH[0][t] + sH[1][t] + b1[t];
        sT[t] = v > 0.f ? v : 0.2f * v;
    }
    __syncthreads();
    {
        const int c = t & 127, hf = t >> 7;
        float acc = 0.f;
        const float* Wp = W2 + (size_t)(hf * 64) * 128 + c;
#pragma unroll 8
        for (int k = 0; k < 64; ++k) acc += sT[hf * 64 + k] * Wp[(size_t)k * 128];
        sH[hf][c] = acc;
    }
    __syncthreads();
    if (t < 128) {
        float nv = vn[(size_t)b * 128 + t] + sH[0][t] + sH[1][t] + b2[t];
        vn[(size_t)b * 128 + t] = nv;
        vnb[(size_t)b * 128 + t] = f2bf(nv);
    }
}

// ---------------- final: pool(bf16 hb0) + BN + fc  (4 batches per block) ----------------
__global__ __launch_bounds__(256) void k_final(
    const u16* __restrict__ hb0, const int* __restrict__ bstart,
    const float* __restrict__ g, const float* __restrict__ bB,
    const float* __restrict__ fcW, const float* __restrict__ fcb,
    float* __restrict__ out) {
    __shared__ float sP[4][128];
    __shared__ float4 red[4][2][32];
    const int t = threadIdx.x;
    const int seg = t >> 6, gq = t & 63, rg = gq >> 5, q = gq & 31;
    const int b = blockIdx.x * 4 + seg;
    const int s = bstart[b], e = bstart[b + 1];
    const uint2* h2 = (const uint2*)hb0;
    float4 a = make_float4(0.f, 0.f, 0.f, 0.f);
    for (int r = s + rg; r < e; r += 2) {
        uint2 v = h2[(size_t)r * 32 + q];
        a.x += bf2f(v.x & 0xFFFFu); a.y += bf2f(v.x >> 16);
        a.z += bf2f(v.y & 0xFFFFu); a.w += bf2f(v.y >> 16);
    }
    red[seg][rg][q] = a;
    __syncthreads();
    if (rg == 0) {
        float4 v = red[seg][1][q];
        a.x += v.x; a.y += v.y; a.z += v.z; a.w += v.w;
        float av[4] = {a.x, a.y, a.z, a.w};
#pragma unroll
        for (int i = 0; i < 4; ++i) {
            int c = q * 4 + i;
            sP[seg][c] = g[c] * av[i] * BNS + bB[c];
        }
    }
    __syncthreads();
    const int o = t & 63;
    float acc = fcb[o];
    const float* wrow = fcW + o * 128;
    const float* prow = sP[seg];
    for (int k = 0; k < 128; ++k) acc += prow[k] * wrow[k];
    out[(size_t)b * 64 + o] = acc;
}

extern "C" void kernel_launch(void* const* d_in, const int* in_sizes, int n_in,
                              void* d_out, int out_size, void* d_ws, size_t ws_size,
                              hipStream_t stream) {
    const float* x       = (const float*)d_in[0];
    const int*   ei      = (const int*)d_in[1];
    const int*   batch   = (const int*)d_in[2];
    const float* node_W  = (const float*)d_in[3];
    const float* node_b  = (const float*)d_in[4];
    const float* conv_W1 = (const float*)d_in[5];
    const float* conv_b1 = (const float*)d_in[6];
    const float* conv_g  = (const float*)d_in[7];
    const float* conv_bt = (const float*)d_in[8];
    const float* conv_W2 = (const float*)d_in[9];
    const float* conv_b2 = (const float*)d_in[10];
    const float* vn_emb  = (const float*)d_in[11];
    const float* vn_W1   = (const float*)d_in[12];
    const float* vn_b1   = (const float*)d_in[13];
    const float* vn_W2   = (const float*)d_in[14];
    const float* vn_b2   = (const float*)d_in[15];
    const float* bn_g    = (const float*)d_in[16];
    const float* bn_b    = (const float*)d_in[17];
    const float* fc_W    = (const float*)d_in[18];
    const float* fc_b    = (const float*)d_in[19];
    float* out = (float*)d_out;

    char* ws = (char*)d_ws;
    u16* hb0   = (u16*)ws;                        // NN*128 bf16 (h, pre-vn)
    u16* aggh  = hb0 + (size_t)NN * 128;          // NN*128 bf16 (agg hi)
    u16* agglo = aggh + (size_t)NN * 128;         // NN*128 bf16 (agg lo)
    u16* wt    = agglo + (size_t)NN * 128;        // 7*WT_M bf16
    u32* nbr   = (u32*)(wt + 7 * WT_M);           // NN*DCAP u32 (padded CSR)
    float* vn  = (float*)(nbr + (size_t)NN * DCAP);  // NB*128 f32
    u16* vnb   = (u16*)(vn + NB * 128);           // NB*128 bf16
    float* counts = (float*)(vnb + NB * 128);     // NB
    int* bstart = (int*)(counts + NB);            // NB+1
    int* deg    = bstart + NB + 1;                // NN  <- zeroed

    hipMemsetAsync(deg, 0, NN * sizeof(int), stream);
    k_prep<<<704, 256, 0, stream>>>(node_W, conv_W1, conv_W2, wt,
                                    vn_emb, vn, vnb, batch, bstart, counts);
    // gemm0 + pcsr co-scheduled (independent workloads, one dispatch)
    k_enc<<<GG0 + PCSR512, 512, 0, stream>>>(x, wt, node_b, hb0, ei, batch, deg, nbr);

    for (int l = 0; l < 3; ++l) {
        k_gather<<<(NN + 15) / 16, 256, 0, stream>>>(deg, nbr, hb0, vnb, batch, aggh, agglo);
        k_conv<<<(NN + 127) / 128, 256, 0, stream>>>(
            aggh, agglo, wt + (size_t)(1 + l) * WT_M, conv_b1 + l * 128,
            conv_g + l * 128, conv_bt + l * 128,
            wt + (size_t)(4 + l) * WT_M, conv_b2 + l * 128, hb0);
        if (l < 2)
            k_vnup<<<NB, 256, 0, stream>>>(hb0, bstart, counts, vn_W1 + l * 16384,
                                           vn_b1 + l * 128, vn_W2 + l * 16384,
                                           vn_b2 + l * 128, vn, vnb);
    }

    k_final<<<NB / 4, 256, 0, stream>>>(hb0, bstart, bn_g, bn_b, fc_W, fc_b, out);
}